// Round 3
// baseline (13696.619 us; speedup 1.0000x reference)
//
#include <hip/hip_runtime.h>
#include <math.h>

// NodeformerProcessor: 3x (nodeformer_conv -> [leaky] -> graph_norm), full fp64.
// v3: y computed via precomputed G[h][m][c] = sum_d kvs[h][m][d]*Wo[h*64+d][c]
//     (k_redkv computes G once per layer) -> k_q loses the 512-term z@Wo dot
//     and the z pass entirely. Kahan kept ONLY on cross-block reductions
//     (v2 showed absmax is insensitive to in-dot compensation). qs padded to
//     kill the 8-way LDS bank conflict. All reductions fixed-order, no atomics.

namespace {

constexpr int N   = 50000;
constexpr int C   = 64;
constexpr int H   = 8;
constexpr int HD  = 512;
constexpr int M   = 30;

constexpr int NT2 = 8;          // nodes/group in k_kv
constexpr int NG2 = N / NT2;    // 6250
constexpr int NB2 = 96;         // blocks per head (8*96=768 = 3/CU)
constexpr int NTQ = 4;          // nodes/group in k_q
constexpr int NGQ = N / NTQ;    // 12500
constexpr int NBQ = 1024;       // k_q grid (4 blocks/CU)
constexpr int PSTR = 2048;      // partial: A[1920] | Es[30] | Sv[64] | max[1]

__device__ constexpr double DN    = 0.35355339059327373;  // 1/sqrt(sqrt(64))
__device__ constexpr double RATIO = 0.18257418583505536;  // 1/sqrt(30)
__device__ constexpr double EPSK  = 1e-6;
__device__ constexpr double EPSN  = 1e-5;

__device__ __forceinline__ void kah(double& s, double& c, double v) {
  double y = v - c; double t = s + y; c = (t - s) - y; s = t;
}

// ---------------- pass 1: per-head A/Es/Sv partials + max(dd) ----------------
template <int LM>  // 0: x from f32 source; 1: x = (y - a)*b + c (norm fold)
__global__ __launch_bounds__(256, 3)
void k_kv(const float* __restrict__ xf, const double* __restrict__ yv,
          const double* __restrict__ nparam,
          const float* __restrict__ Wk, const float* __restrict__ bk,
          const float* __restrict__ Wv, const float* __restrict__ bv,
          const float* __restrict__ P, double* __restrict__ partial) {
  __shared__ float wks[64][64];       // [c][j] slice for this head
  __shared__ float wvs[64][64];
  __shared__ double xs[NT2][64], ks[NT2][64], vs[NT2][64];
  __shared__ double kpl[NT2][M];
  __shared__ double diag[NT2];
  __shared__ double red[256];
  const int t = threadIdx.x, i0 = t >> 6, c0 = t & 63;
  const int h = blockIdx.x / NB2, b = blockIdx.x % NB2, hb = h * 64;

  for (int s = t; s < 4096; s += 256) {
    const int c = s >> 6, j = s & 63;
    wks[c][j] = Wk[c * HD + hb + j];
    wvs[c][j] = Wv[c * HD + hb + j];
  }
  const double bk0 = (double)bk[hb + c0], bv0 = (double)bv[hb + c0];
  double npa = 0, npb = 0, npc = 0;
  if (LM == 1) { npa = nparam[c0]; npb = nparam[64 + c0]; npc = nparam[128 + c0]; }
  double acc8[8];
#pragma unroll
  for (int k = 0; k < 8; ++k) acc8[k] = 0.0;
  double ssv = 0, ses = 0, runmax = -1e300;
  __syncthreads();

  for (int g = b; g < NG2; g += NB2) {
    const int n0 = g * NT2;
    {
      const size_t gi0 = (size_t)(n0 + i0) * C + c0;
      const size_t gi1 = (size_t)(n0 + i0 + 4) * C + c0;
      double x0, x1;
      if (LM == 0) { x0 = (double)xf[gi0]; x1 = (double)xf[gi1]; }
      else {
        x0 = (yv[gi0] - npa) * npb + npc;
        x1 = (yv[gi1] - npa) * npb + npc;
      }
      xs[i0][c0] = x0; xs[i0 + 4][c0] = x1;
    }
    __syncthreads();
    // k,v projection for this head: 2 nodes per thread, weights from LDS
    double ka0 = bk0, ka1 = bk0, va0 = bv0, va1 = bv0;
    for (int c = 0; c < 64; ++c) {
      const double wk = (double)wks[c][c0], wv = (double)wvs[c][c0];
      const double x0 = xs[i0][c], x1 = xs[i0 + 4][c];
      ka0 = fma(x0, wk, ka0); ka1 = fma(x1, wk, ka1);
      va0 = fma(x0, wv, va0); va1 = fma(x1, wv, va1);
    }
    ks[i0][c0] = ka0; ks[i0 + 4][c0] = ka1;
    vs[i0][c0] = va0; vs[i0 + 4][c0] = va1;
    // diag_k via wave butterfly (sum of k^2 over the 64 lanes)
    double q0 = ka0 * ka0, q1 = ka1 * ka1;
#pragma unroll
    for (int off = 32; off; off >>= 1) {
      q0 += __shfl_xor(q0, off, 64);
      q1 += __shfl_xor(q1, off, 64);
    }
    if (c0 == 0) { diag[i0] = q0 * (DN * DN * 0.5); diag[i0 + 4] = q1 * (DN * DN * 0.5); }
    ssv += va0 + va1;  // Sv[c0] partial
    __syncthreads();
    // dd_k -> max track -> E = exp(dd - diag)   (stab applied later)
    if (t < NT2 * M) {
      const int i = t / M, m = t - i * M;
      double a = 0.0;
      for (int d = 0; d < 64; ++d) a = fma(ks[i][d], (double)P[m * C + d], a);
      a *= DN;
      runmax = fmax(runmax, a);
      kpl[i][m] = exp(a - diag[i]);
    }
    __syncthreads();
    if (t < M) {  // Es[m] partial
      double gsum = 0.0;
#pragma unroll
      for (int i = 0; i < NT2; ++i) gsum += kpl[i][t];
      ses += gsum;
    }
    // A[m][d] += E[i][m]*v[i][d]  (d = c0; slots over m)
    double vr[NT2];
#pragma unroll
    for (int i = 0; i < NT2; ++i) vr[i] = vs[i][c0];
#pragma unroll
    for (int k = 0; k < 8; ++k) {
      const int s = t + (k << 8);
      if (s < M * 64) {
        const int m = s >> 6;
        double gsum = acc8[k];
#pragma unroll
        for (int i = 0; i < NT2; ++i) gsum = fma(kpl[i][m], vr[i], gsum);
        acc8[k] = gsum;
      }
    }
    __syncthreads();
  }
  // block-level outputs
  const size_t base = (size_t)blockIdx.x * PSTR;
  __syncthreads();
  red[t] = ssv;
  __syncthreads();
  if (t < 64) partial[base + 1950 + t] = red[t] + red[t + 64] + red[t + 128] + red[t + 192];
  __syncthreads();
  red[t] = runmax;
  __syncthreads();
  for (int off = 128; off; off >>= 1) {
    if (t < off) red[t] = fmax(red[t], red[t + off]);
    __syncthreads();
  }
  if (t == 0) partial[base + 2014] = red[0];
  if (t < M) partial[base + 1920 + t] = ses;
#pragma unroll
  for (int k = 0; k < 8; ++k) {
    const int s = t + (k << 8);
    if (s < M * 64) partial[base + s] = acc8[k];
  }
}

// ------- pass 2: reduce partials, apply stab/eps, precompute G = kvs@Wo -------
__global__ __launch_bounds__(256)
void k_redkv(const double* __restrict__ partial, const float* __restrict__ Wo,
             double* __restrict__ ksumg, double* __restrict__ Gg) {
  const int h = blockIdx.x, t = threadIdx.x;
  __shared__ double red[128];
  __shared__ double svt[64];
  __shared__ double kvls[M * 64];
  __shared__ double escs;
  const size_t hb = (size_t)h * NB2;
  if (t < 128) red[t] = (t < NB2) ? partial[(hb + t) * PSTR + 2014] : -1e300;
  __syncthreads();
  for (int off = 64; off; off >>= 1) {
    if (t < off) red[t] = fmax(red[t], red[t + off]);
    __syncthreads();
  }
  if (t == 0) escs = exp(-red[0]);
  __syncthreads();
  const double esc = escs;
  if (t < 64) {
    double s = 0, c = 0;
    for (int b = 0; b < NB2; ++b) kah(s, c, partial[(hb + b) * PSTR + 1950 + t]);
    svt[t] = s - c;
  } else if (t < 64 + M) {
    const int m = t - 64;
    double s = 0, c = 0;
    for (int b = 0; b < NB2; ++b) kah(s, c, partial[(hb + b) * PSTR + 1920 + m]);
    ksumg[h * M + m] = RATIO * (esc * (s - c) + EPSK * (double)N);
  }
  __syncthreads();
#pragma unroll
  for (int k = 0; k < 8; ++k) {
    const int sidx = t + (k << 8);
    if (sidx < M * 64) {
      double s = 0, c = 0;
      for (int b = 0; b < NB2; ++b) kah(s, c, partial[(hb + b) * PSTR + sidx]);
      kvls[sidx] = RATIO * (esc * (s - c) + EPSK * svt[sidx & 63]);
    }
  }
  __syncthreads();
  // G[m][c] = sum_d kvs[m][d] * Wo[(h*64+d)*64 + c]
#pragma unroll
  for (int k = 0; k < 8; ++k) {
    const int sidx = t + (k << 8);
    if (sidx < M * 64) {
      const int m = sidx >> 6, c = sidx & 63;
      double a = 0.0;
      for (int d = 0; d < 64; ++d)
        a = fma(kvls[m * 64 + d], (double)Wo[(h * 64 + d) * 64 + c], a);
      Gg[(size_t)h * (M * 64) + sidx] = a;
    }
  }
}

// ---------------- pass 3: q / qp / y / column sums ----------------
template <int LM>
__global__ __launch_bounds__(256, 4)
void k_q(const float* __restrict__ xf, const double* __restrict__ nparam,
         const float* __restrict__ Wq, const float* __restrict__ bq,
         const float* __restrict__ P, const double* __restrict__ Gg,
         const double* __restrict__ ksumg, const float* __restrict__ bo,
         int do_leaky, double* __restrict__ y, double* __restrict__ psum) {
  __shared__ double xs[NTQ][C];
  __shared__ double qs[NTQ][H][66];        // padded: h-groups on distinct banks
  __shared__ double qps[NTQ][H * M];
  __shared__ double stabl[NTQ][H], diagl[NTQ][H], rdenl[NTQ][H];
  const int t = threadIdx.x, i0 = t >> 6, c0 = t & 63;
  double bq8[8];
#pragma unroll
  for (int k = 0; k < 8; ++k) bq8[k] = (double)bq[c0 + 64 * k];
  const double bo0 = (double)bo[c0];
  double npa = 0, npb = 0, npc = 0;
  if (LM == 1) { npa = nparam[c0]; npb = nparam[64 + c0]; npc = nparam[128 + c0]; }
  double sy = 0, csy = 0, sy2 = 0, csy2 = 0;

  for (int g = blockIdx.x; g < NGQ; g += NBQ) {
    const int n0 = g * NTQ;
    __syncthreads();  // protect xs/qs/qps reuse
    {
      const size_t gi = (size_t)(n0 + i0) * C + c0;
      xs[i0][c0] = (LM == 0) ? (double)xf[gi] : (y[gi] - npa) * npb + npc;
    }
    __syncthreads();
    // q = x @ Wq + bq   (thread (i0,c0) -> q[i0][h=k][d=c0] for all k)
    double acc[8];
#pragma unroll
    for (int k = 0; k < 8; ++k) acc[k] = bq8[k];
    for (int c = 0; c < C; ++c) {
      const double xv = xs[i0][c];
#pragma unroll
      for (int k = 0; k < 8; ++k)
        acc[k] = fma(xv, (double)Wq[c * HD + c0 + 64 * k], acc[k]);
    }
#pragma unroll
    for (int k = 0; k < 8; ++k) qs[i0][k][c0] = acc[k];
    __syncthreads();
    // dd_q
    for (int s = t; s < NTQ * H * M; s += 256) {
      const int i = s / (H * M), hm = s % (H * M), h = hm / M, m = hm % M;
      double a = 0.0;
      for (int d = 0; d < C; ++d) a = fma(qs[i][h][d], (double)P[m * C + d], a);
      qps[i][hm] = a * DN;
    }
    __syncthreads();
    if (t < NTQ * H) {  // per-(n,h) stab + diag
      const int i = t >> 3, h = t & 7;
      double mx = qps[i][h * M];
      for (int m = 1; m < M; ++m) mx = fmax(mx, qps[i][h * M + m]);
      double ss = 0.0;
      for (int d = 0; d < C; ++d) { const double q = qs[i][h][d]; ss = fma(q, q, ss); }
      stabl[i][h] = mx;
      diagl[i][h] = ss * (DN * DN * 0.5);
    }
    __syncthreads();
    for (int s = t; s < NTQ * H * M; s += 256) {
      const int i = s / (H * M), hm = s % (H * M), h = hm / M;
      qps[i][hm] = RATIO * (exp((qps[i][hm] - diagl[i][h]) - stabl[i][h]) + EPSK);
    }
    __syncthreads();
    if (t < NTQ * H) {  // 1/den
      const int i = t >> 3, h = t & 7;
      double a = 0.0;
      for (int m = 0; m < M; ++m) a = fma(qps[i][h * M + m], ksumg[h * M + m], a);
      rdenl[i][h] = 1.0 / a;
    }
    __syncthreads();
    // y = bo + sum_h rden[h] * (qp[h,:] @ G[h,:,c0]),  leaky, store, col sums
    {
      double ah[8];
#pragma unroll
      for (int h = 0; h < 8; ++h) {
        const double* gp = Gg + (size_t)h * (M * 64) + c0;
        const double* qp = &qps[i0][h * M];
        double s0 = 0.0, s1 = 0.0;
        for (int m = 0; m < M; m += 2) {
          s0 = fma(qp[m],     gp[(size_t)m * 64],       s0);
          s1 = fma(qp[m + 1], gp[(size_t)(m + 1) * 64], s1);
        }
        ah[h] = s0 + s1;
      }
      double a = bo0;
#pragma unroll
      for (int h = 0; h < 8; ++h) a = fma(rdenl[i0][h], ah[h], a);
      if (do_leaky) a = (a >= 0.0) ? a : 0.01 * a;
      y[(size_t)(n0 + i0) * C + c0] = a;
      kah(sy, csy, a);
      kah(sy2, csy2, a * a);
    }
  }
  __syncthreads();
  xs[i0][c0] = sy - csy;
  __syncthreads();
  if (t < C) psum[(size_t)blockIdx.x * 128 + t] = xs[0][t] + xs[1][t] + xs[2][t] + xs[3][t];
  __syncthreads();
  xs[i0][c0] = sy2 - csy2;
  __syncthreads();
  if (t < C) psum[(size_t)blockIdx.x * 128 + 64 + t] = xs[0][t] + xs[1][t] + xs[2][t] + xs[3][t];
}

// ---------------- graph-norm parameters ----------------
__global__ void k_norm_params(const double* __restrict__ psum,
                              const float* __restrict__ gamma, const float* __restrict__ beta,
                              const float* __restrict__ alpha, double* __restrict__ nparam) {
  const int t = threadIdx.x;
  __shared__ double m1l[64], m2l[64];
  if (t < 64) {
    double s = 0, c = 0;
    for (int b = 0; b < NBQ; ++b) kah(s, c, psum[(size_t)b * 128 + t]);
    m1l[t] = s - c;
  } else if (t < 128) {
    const int ci = t - 64;
    double s = 0, c = 0;
    for (int b = 0; b < NBQ; ++b) kah(s, c, psum[(size_t)b * 128 + 64 + ci]);
    m2l[ci] = s - c;
  }
  __syncthreads();
  if (t < 64) {
    const double mu = m1l[t] / (double)N;
    const double m2 = m2l[t] / (double)N;
    const double al = (double)alpha[t];
    double var = m2 - (2.0 * al - al * al) * mu * mu;
    if (var < 0.0) var = 0.0;
    nparam[t]       = al * mu;
    nparam[64 + t]  = (double)gamma[t] / sqrt(var + EPSN);
    nparam[128 + t] = (double)beta[t];
  }
}

// ---------------- final normalize -> f32 output (layer 3 only) ----------------
__global__ void k_normalize(const double* __restrict__ yv, const double* __restrict__ nparam,
                            float* __restrict__ out) {
  const int total = N * C;
  for (int i = blockIdx.x * blockDim.x + threadIdx.x; i < total; i += gridDim.x * blockDim.x) {
    const int c = i & 63;
    out[i] = (float)((yv[i] - nparam[c]) * nparam[64 + c] + nparam[128 + c]);
  }
}

}  // namespace

extern "C" void kernel_launch(void* const* d_in, const int* in_sizes, int n_in,
                              void* d_out, int out_size, void* d_ws, size_t ws_size,
                              hipStream_t stream) {
  const float* patch = (const float*)d_in[0];
  // d_in[1] edge_index, d_in[2] edge_attr: unused by the reference
  const float* Wq = (const float*)d_in[3];
  const float* Wk = (const float*)d_in[4];
  const float* Wv = (const float*)d_in[5];
  const float* Wo = (const float*)d_in[6];
  const float* bq = (const float*)d_in[7];
  const float* bk = (const float*)d_in[8];
  const float* bv = (const float*)d_in[9];
  const float* bo = (const float*)d_in[10];
  const float* P  = (const float*)d_in[11];
  const float* ga = (const float*)d_in[12];
  const float* be = (const float*)d_in[13];
  const float* al = (const float*)d_in[14];
  float* out = (float*)d_out;

  // workspace (doubles): ~40 MB
  double* ws      = (double*)d_ws;
  double* y       = ws;                                   // N*C
  double* partial = y + (size_t)N * C;                    // 768*PSTR
  double* ksumg   = partial + (size_t)(H * NB2) * PSTR;   // H*M
  double* Gg      = ksumg + (size_t)H * M;                // H*M*64
  double* psum    = Gg + (size_t)H * M * 64;              // NBQ*128
  double* nparam  = psum + (size_t)NBQ * 128;             // 192

  for (int L = 0; L < 3; ++L) {
    const float* wq  = Wq + (size_t)L * C * HD;
    const float* wk  = Wk + (size_t)L * C * HD;
    const float* wv  = Wv + (size_t)L * C * HD;
    const float* wo  = Wo + (size_t)L * HD * C;
    const float* bq_ = bq + (size_t)L * HD;
    const float* bk_ = bk + (size_t)L * HD;
    const float* bv_ = bv + (size_t)L * HD;
    const float* bo_ = bo + (size_t)L * C;
    const float* p   = P  + (size_t)L * M * C;

    if (L == 0)
      k_kv<0><<<H * NB2, 256, 0, stream>>>(patch, nullptr, nparam, wk, bk_, wv, bv_, p, partial);
    else
      k_kv<1><<<H * NB2, 256, 0, stream>>>(nullptr, y, nparam, wk, bk_, wv, bv_, p, partial);

    k_redkv<<<H, 256, 0, stream>>>(partial, wo, ksumg, Gg);

    if (L == 0)
      k_q<0><<<NBQ, 256, 0, stream>>>(patch, nparam, wq, bq_, p, Gg, ksumg, bo_,
                                      1, y, psum);
    else
      k_q<1><<<NBQ, 256, 0, stream>>>(nullptr, nparam, wq, bq_, p, Gg, ksumg, bo_,
                                      (L < 2) ? 1 : 0, y, psum);

    k_norm_params<<<1, 128, 0, stream>>>(psum, ga + (size_t)L * C, be + (size_t)L * C,
                                         al + (size_t)L * C, nparam);
    if (L == 2)
      k_normalize<<<512, 256, 0, stream>>>(y, nparam, out);
  }
}

// Round 4
// 5902.995 us; speedup vs baseline: 2.3203x; 2.3203x over previous
//
#include <hip/hip_runtime.h>
#include <math.h>

// NodeformerProcessor: 3x (nodeformer_conv -> [leaky] -> graph_norm), full fp64.
// v4: every per-iteration-reused operand is LDS-resident (v3 showed 2.9GB
//     HBM fetch from G/Wq re-streaming). k_q split into:
//       k_qp: 2-head families, Wq slice + P in LDS, writes rden-scaled qp'
//             in node-quarter rounds (ws stays < 59MB);
//       k_y : y = bo + qp' @ G with G fully LDS-resident (123KB dynamic LDS),
//             fused leaky + column sums.
//     k_kv: P staged in LDS, xs via __shfl. All reductions fixed-order.

namespace {

constexpr int N   = 50000;
constexpr int C   = 64;
constexpr int H   = 8;
constexpr int HD  = 512;
constexpr int M   = 30;

constexpr int NT2 = 8;             // nodes/group in k_kv
constexpr int NG2 = N / NT2;       // 6250
constexpr int NB2 = 64;            // blocks per head in k_kv (grid 512)
constexpr int PSTR = 2048;         // partial: A[0..1920) | Es@1920 | Sv@1950 | max@2014

constexpr int ROUNDS = 4;
constexpr int RNODES = N / ROUNDS; // 12500
constexpr int RGRP   = RNODES / 4; // 3125 groups of 4 nodes (k_qp)
constexpr int NBY    = 512;        // k_y grid / psum rows

__device__ constexpr double DN    = 0.35355339059327373;  // 1/sqrt(sqrt(64))
__device__ constexpr double RATIO = 0.18257418583505536;  // 1/sqrt(30)
__device__ constexpr double EPSK  = 1e-6;
__device__ constexpr double EPSN  = 1e-5;

__device__ __forceinline__ void kah(double& s, double& c, double v) {
  double y = v - c; double t = s + y; c = (t - s) - y; s = t;
}

// ---------------- pass 1: per-head A/Es/Sv partials + max(dd) ----------------
template <int LM>  // 0: x from f32 source; 1: x = (y - a)*b + c (norm fold)
__global__ __launch_bounds__(256, 2)
void k_kv(const float* __restrict__ xf, const double* __restrict__ yv,
          const double* __restrict__ nparam,
          const float* __restrict__ Wk, const float* __restrict__ bk,
          const float* __restrict__ Wv, const float* __restrict__ bv,
          const float* __restrict__ P, double* __restrict__ partial) {
  __shared__ float wks[64 * 64];          // [c][j] slice for this head
  __shared__ float wvs[64 * 64];
  __shared__ double ks[NT2][64], vs[NT2][64];
  __shared__ double kpl[NT2][M];
  __shared__ double diag[NT2];
  __shared__ double pd[30 * 67];          // padded fp64 P
  const int t = threadIdx.x, i0 = t >> 6, c0 = t & 63;
  const int h = blockIdx.x / NB2, b = blockIdx.x % NB2, hb = h * 64;

  for (int s = t; s < 4096; s += 256) {
    const int c = s >> 6, j = s & 63;
    wks[s] = Wk[c * HD + hb + j];
    wvs[s] = Wv[c * HD + hb + j];
  }
  for (int s = t; s < 1920; s += 256) {
    const int m = s / 64, d = s - m * 64;
    pd[m * 67 + d] = (double)P[s];
  }
  const double bk0 = (double)bk[hb + c0], bv0 = (double)bv[hb + c0];
  double npa = 0, npb = 0, npc = 0;
  if (LM == 1) { npa = nparam[c0]; npb = nparam[64 + c0]; npc = nparam[128 + c0]; }
  double acc8[8];
#pragma unroll
  for (int k = 0; k < 8; ++k) acc8[k] = 0.0;
  double ssv = 0, ses = 0, runmax = -1e300;
  __syncthreads();

  for (int g = b; g < NG2; g += NB2) {
    const int n0 = g * NT2;
    const size_t gi0 = (size_t)(n0 + i0) * C + c0;
    const size_t gi1 = (size_t)(n0 + i0 + 4) * C + c0;
    double x0, x1;
    if (LM == 0) { x0 = (double)xf[gi0]; x1 = (double)xf[gi1]; }
    else {
      x0 = (yv[gi0] - npa) * npb + npc;
      x1 = (yv[gi1] - npa) * npb + npc;
    }
    // k,v projection for this head (x broadcast via shuffles, weights LDS)
    double ka0 = bk0, ka1 = bk0, va0 = bv0, va1 = bv0;
    for (int c = 0; c < 64; ++c) {
      const double xv0 = __shfl(x0, c, 64), xv1 = __shfl(x1, c, 64);
      const double wk = (double)wks[c * 64 + c0], wv = (double)wvs[c * 64 + c0];
      ka0 = fma(xv0, wk, ka0); ka1 = fma(xv1, wk, ka1);
      va0 = fma(xv0, wv, va0); va1 = fma(xv1, wv, va1);
    }
    ks[i0][c0] = ka0; ks[i0 + 4][c0] = ka1;
    vs[i0][c0] = va0; vs[i0 + 4][c0] = va1;
    // diag_k via wave butterfly
    double q0 = ka0 * ka0, q1 = ka1 * ka1;
#pragma unroll
    for (int off = 32; off; off >>= 1) {
      q0 += __shfl_xor(q0, off, 64);
      q1 += __shfl_xor(q1, off, 64);
    }
    if (c0 == 0) { diag[i0] = q0 * (DN * DN * 0.5); diag[i0 + 4] = q1 * (DN * DN * 0.5); }
    ssv += va0 + va1;  // Sv[c0] partial
    __syncthreads();
    // dd_k -> max track -> E = exp(dd - diag)  (stab factored out, applied later)
    if (t < NT2 * M) {
      const int i = t / M, m = t - i * M;
      double a = 0.0;
      for (int d = 0; d < 64; ++d) a = fma(ks[i][d], pd[m * 67 + d], a);
      a *= DN;
      runmax = fmax(runmax, a);
      kpl[i][m] = exp(a - diag[i]);
    }
    __syncthreads();
    if (t < M) {  // Es[m] partial (thread t owns m=t)
      double gsum = 0.0;
#pragma unroll
      for (int i = 0; i < NT2; ++i) gsum += kpl[i][t];
      ses += gsum;
    }
    // A[m][d] += E[i][m]*v[i][d]
    double vr[NT2];
#pragma unroll
    for (int i = 0; i < NT2; ++i) vr[i] = vs[i][c0];
#pragma unroll
    for (int k = 0; k < 8; ++k) {
      const int s = t + (k << 8);
      if (s < M * 64) {
        const int m = s >> 6;
        double gsum = acc8[k];
#pragma unroll
        for (int i = 0; i < NT2; ++i) gsum = fma(kpl[i][m], vr[i], gsum);
        acc8[k] = gsum;
      }
    }
    __syncthreads();
  }
  // block-level outputs (reuse ks / vs as scratch)
  const size_t base = (size_t)blockIdx.x * PSTR;
  double* ksf = &ks[0][0];
  double* vsf = &vs[0][0];
  ksf[t] = ssv;
  vsf[t] = runmax;
  __syncthreads();
  if (t < 64) partial[base + 1950 + t] = ksf[t] + ksf[t + 64] + ksf[t + 128] + ksf[t + 192];
  for (int off = 128; off; off >>= 1) {
    if (t < off) vsf[t] = fmax(vsf[t], vsf[t + off]);
    __syncthreads();
  }
  if (t == 0) partial[base + 2014] = vsf[0];
  if (t < M) partial[base + 1920 + t] = ses;
#pragma unroll
  for (int k = 0; k < 8; ++k) {
    const int s = t + (k << 8);
    if (s < M * 64) partial[base + s] = acc8[k];
  }
}

// ------- pass 2: reduce partials, apply stab/eps, precompute G = kvs@Wo -------
__global__ __launch_bounds__(256)
void k_redkv(const double* __restrict__ partial, const float* __restrict__ Wo,
             double* __restrict__ ksumg, double* __restrict__ Gg) {
  const int h = blockIdx.x, t = threadIdx.x;
  __shared__ double red[128];
  __shared__ double svt[64];
  __shared__ double kvls[M * 64];
  __shared__ double escs;
  const size_t hb = (size_t)h * NB2;
  if (t < 128) red[t] = (t < NB2) ? partial[(hb + t) * PSTR + 2014] : -1e300;
  __syncthreads();
  for (int off = 64; off; off >>= 1) {
    if (t < off) red[t] = fmax(red[t], red[t + off]);
    __syncthreads();
  }
  if (t == 0) escs = exp(-red[0]);
  __syncthreads();
  const double esc = escs;
  if (t < 64) {
    double s = 0, c = 0;
    for (int b = 0; b < NB2; ++b) kah(s, c, partial[(hb + b) * PSTR + 1950 + t]);
    svt[t] = s - c;
  } else if (t < 64 + M) {
    const int m = t - 64;
    double s = 0, c = 0;
    for (int b = 0; b < NB2; ++b) kah(s, c, partial[(hb + b) * PSTR + 1920 + m]);
    ksumg[h * M + m] = RATIO * (esc * (s - c) + EPSK * (double)N);
  }
  __syncthreads();
#pragma unroll
  for (int k = 0; k < 8; ++k) {
    const int sidx = t + (k << 8);
    if (sidx < M * 64) {
      double s = 0, c = 0;
      for (int b = 0; b < NB2; ++b) kah(s, c, partial[(hb + b) * PSTR + sidx]);
      kvls[sidx] = RATIO * (esc * (s - c) + EPSK * svt[sidx & 63]);
    }
  }
  __syncthreads();
  // G[m][c] = sum_d kvs[m][d] * Wo[(h*64+d)*64 + c]
#pragma unroll
  for (int k = 0; k < 8; ++k) {
    const int sidx = t + (k << 8);
    if (sidx < M * 64) {
      const int m = sidx >> 6, c = sidx & 63;
      double a = 0.0;
      for (int d = 0; d < 64; ++d)
        a = fma(kvls[m * 64 + d], (double)Wo[(h * 64 + d) * 64 + c], a);
      Gg[(size_t)h * (M * 64) + sidx] = a;
    }
  }
}

// ------- pass 3a: qp' = rden * qp for a node-quarter (2-head families) -------
template <int LM>
__global__ __launch_bounds__(256, 3)
void k_qp(const float* __restrict__ xf, const double* __restrict__ yv,
          const double* __restrict__ nparam,
          const float* __restrict__ Wq, const float* __restrict__ bq,
          const float* __restrict__ P, const double* __restrict__ ksumg,
          double* __restrict__ qpq, int rbase) {
  __shared__ float wqs[64 * 128];         // Wq columns for this head pair
  __shared__ float psf[30 * 67];
  __shared__ double qs[4][2][65];
  __shared__ double qps[4][60];
  __shared__ double stabd[4][2], diagd[4][2], rdend[4][2];
  __shared__ double ksl[60];
  const int t = threadIdx.x, i0 = t >> 6, c0 = t & 63;
  const int hp = blockIdx.x & 3, blk = blockIdx.x >> 2;

  for (int s = t; s < 8192; s += 256) {
    const int c = s >> 7, j = s & 127;
    wqs[s] = Wq[c * HD + hp * 128 + j];
  }
  for (int s = t; s < 1920; s += 256) {
    const int m = s / 64, d = s - m * 64;
    psf[m * 67 + d] = P[s];
  }
  if (t < 60) ksl[t] = ksumg[hp * 60 + t];
  const double bqA = (double)bq[hp * 128 + c0];
  const double bqB = (double)bq[hp * 128 + 64 + c0];
  double npa = 0, npb = 0, npc = 0;
  if (LM == 1) { npa = nparam[c0]; npb = nparam[64 + c0]; npc = nparam[128 + c0]; }
  __syncthreads();

  for (int g = blk; g < RGRP; g += 256) {
    const int n0 = rbase + g * 4;
    const size_t gi = (size_t)(n0 + i0) * C + c0;
    double x0 = (LM == 0) ? (double)xf[gi] : (yv[gi] - npa) * npb + npc;
    double a0 = bqA, a1 = bqB;
    for (int c = 0; c < 64; ++c) {
      const double xv = __shfl(x0, c, 64);
      a0 = fma(xv, (double)wqs[c * 128 + c0], a0);
      a1 = fma(xv, (double)wqs[c * 128 + 64 + c0], a1);
    }
    qs[i0][0][c0] = a0;
    qs[i0][1][c0] = a1;
    __syncthreads();
    if (t < 240) {  // dd_q (raw)
      const int i = t / 60, r = t - i * 60, hl = r / 30, m = r - hl * 30;
      double a = 0.0;
      for (int d = 0; d < 64; ++d) a = fma(qs[i][hl][d], (double)psf[m * 67 + d], a);
      qps[i][r] = a * DN;
    }
    __syncthreads();
    if (t < 8) {  // per-(n,h) stab + diag
      const int i = t >> 1, hl = t & 1;
      double mx = qps[i][hl * 30];
      for (int m = 1; m < 30; ++m) mx = fmax(mx, qps[i][hl * 30 + m]);
      double ss = 0.0;
      for (int d = 0; d < 64; ++d) { const double q = qs[i][hl][d]; ss = fma(q, q, ss); }
      stabd[i][hl] = mx;
      diagd[i][hl] = ss * (DN * DN * 0.5);
    }
    __syncthreads();
    if (t < 240) {  // qp
      const int i = t / 60, r = t - i * 60, hl = r / 30;
      qps[i][r] = RATIO * (exp((qps[i][r] - diagd[i][hl]) - stabd[i][hl]) + EPSK);
    }
    __syncthreads();
    if (t < 8) {  // 1/den
      const int i = t >> 1, hl = t & 1;
      double a = 0.0;
      for (int m = 0; m < 30; ++m) a = fma(qps[i][hl * 30 + m], ksl[hl * 30 + m], a);
      rdend[i][hl] = 1.0 / a;
    }
    __syncthreads();
    if (t < 240) {  // write rden-scaled qp'
      const int i = t / 60, r = t - i * 60, hl = r / 30;
      qpq[(size_t)(n0 + i - rbase) * 240 + hp * 60 + r] = qps[i][r] * rdend[i][hl];
    }
    // no trailing sync needed: next write to qps is after the post-proj sync
  }
}

// ------- pass 3b: y = bo + qp' @ G (G LDS-resident), leaky, column sums -------
__global__ __launch_bounds__(1024, 1)
void k_y(const double* __restrict__ qpq, const double* __restrict__ Gg,
         const float* __restrict__ bo, int do_leaky,
         double* __restrict__ y, double* __restrict__ psum,
         int rbase, int round) {
  extern __shared__ double sm[];
  double* Gl  = sm;            // 240*64 = 15360
  double* qpl = sm + 15360;    // 32*120 = 3840 (also reused for reductions)
  const int t = threadIdx.x, i0 = t >> 6, c0 = t & 63;
  for (int s = t; s < 15360; s += 1024) Gl[s] = Gg[s];
  const double bo0 = (double)bo[c0];
  const int rend = rbase + RNODES;
  double sy = 0, sy2 = 0;
  __syncthreads();

  const int nchunks = (RNODES + 31) / 32;  // 391
  for (int ch = blockIdx.x; ch < nchunks; ch += gridDim.x) {
    const int base = rbase + ch * 32;
    const int na = base + i0, nb = base + 16 + i0;
    double acca = bo0, accb = bo0;
    for (int ph = 0; ph < 2; ++ph) {
      __syncthreads();
      for (int s = t; s < 3840; s += 1024) {
        const int ni = s / 120, jj = s - ni * 120;
        const int n = base + ni;
        qpl[s] = (n < rend) ? qpq[(size_t)(n - rbase) * 240 + ph * 120 + jj] : 0.0;
      }
      __syncthreads();
      const double* qa = qpl + i0 * 120;
      const double* qb = qpl + (16 + i0) * 120;
      const double* gl = Gl + ph * 120 * 64 + c0;
      for (int j = 0; j < 120; ++j) {
        const double gv = gl[(size_t)j * 64];
        acca = fma(qa[j], gv, acca);
        accb = fma(qb[j], gv, accb);
      }
    }
    if (do_leaky) {
      acca = (acca >= 0.0) ? acca : 0.01 * acca;
      accb = (accb >= 0.0) ? accb : 0.01 * accb;
    }
    if (na < rend) { y[(size_t)na * C + c0] = acca; sy += acca; sy2 = fma(acca, acca, sy2); }
    if (nb < rend) { y[(size_t)nb * C + c0] = accb; sy += accb; sy2 = fma(accb, accb, sy2); }
  }
  // column sums -> psum (accumulated across rounds, init at round 0)
  __syncthreads();
  qpl[t] = sy;
  __syncthreads();
  if (t < 64) {
    double s = 0.0;
    for (int r = 0; r < 16; ++r) s += qpl[c0 + 64 * r];
    const size_t pi = (size_t)blockIdx.x * 128 + c0;
    psum[pi] = (round == 0) ? s : psum[pi] + s;
  }
  __syncthreads();
  qpl[t] = sy2;
  __syncthreads();
  if (t < 64) {
    double s = 0.0;
    for (int r = 0; r < 16; ++r) s += qpl[c0 + 64 * r];
    const size_t pi = (size_t)blockIdx.x * 128 + 64 + c0;
    psum[pi] = (round == 0) ? s : psum[pi] + s;
  }
}

// ---------------- graph-norm parameters ----------------
__global__ void k_norm_params(const double* __restrict__ psum,
                              const float* __restrict__ gamma, const float* __restrict__ beta,
                              const float* __restrict__ alpha, double* __restrict__ nparam) {
  const int t = threadIdx.x;
  __shared__ double m1l[64], m2l[64];
  if (t < 64) {
    double s = 0, c = 0;
    for (int b = 0; b < NBY; ++b) kah(s, c, psum[(size_t)b * 128 + t]);
    m1l[t] = s - c;
  } else if (t < 128) {
    const int ci = t - 64;
    double s = 0, c = 0;
    for (int b = 0; b < NBY; ++b) kah(s, c, psum[(size_t)b * 128 + 64 + ci]);
    m2l[ci] = s - c;
  }
  __syncthreads();
  if (t < 64) {
    const double mu = m1l[t] / (double)N;
    const double m2 = m2l[t] / (double)N;
    const double al = (double)alpha[t];
    double var = m2 - (2.0 * al - al * al) * mu * mu;
    if (var < 0.0) var = 0.0;
    nparam[t]       = al * mu;
    nparam[64 + t]  = (double)gamma[t] / sqrt(var + EPSN);
    nparam[128 + t] = (double)beta[t];
  }
}

// ---------------- final normalize -> f32 output (layer 3 only) ----------------
__global__ void k_normalize(const double* __restrict__ yv, const double* __restrict__ nparam,
                            float* __restrict__ out) {
  const int total = N * C;
  for (int i = blockIdx.x * blockDim.x + threadIdx.x; i < total; i += gridDim.x * blockDim.x) {
    const int c = i & 63;
    out[i] = (float)((yv[i] - nparam[c]) * nparam[64 + c] + nparam[128 + c]);
  }
}

}  // namespace

extern "C" void kernel_launch(void* const* d_in, const int* in_sizes, int n_in,
                              void* d_out, int out_size, void* d_ws, size_t ws_size,
                              hipStream_t stream) {
  const float* patch = (const float*)d_in[0];
  // d_in[1] edge_index, d_in[2] edge_attr: unused by the reference
  const float* Wq = (const float*)d_in[3];
  const float* Wk = (const float*)d_in[4];
  const float* Wv = (const float*)d_in[5];
  const float* Wo = (const float*)d_in[6];
  const float* bq = (const float*)d_in[7];
  const float* bk = (const float*)d_in[8];
  const float* bv = (const float*)d_in[9];
  const float* bo = (const float*)d_in[10];
  const float* P  = (const float*)d_in[11];
  const float* ga = (const float*)d_in[12];
  const float* be = (const float*)d_in[13];
  const float* al = (const float*)d_in[14];
  float* out = (float*)d_out;

  // workspace (doubles): ~58.6 MB
  double* ws      = (double*)d_ws;
  double* y       = ws;                                   // N*C            = 3.2e6
  double* partial = y + (size_t)N * C;                    // 512*PSTR       = 1.049e6
  double* ksumg   = partial + (size_t)(H * NB2) * PSTR;   // H*M            = 240
  double* Gg      = ksumg + (size_t)H * M;                // H*M*64         = 15360
  double* qpq     = Gg + (size_t)H * M * 64;              // RNODES*240     = 3e6
  double* psum    = qpq + (size_t)RNODES * 240;           // NBY*128        = 65536
  double* nparam  = psum + (size_t)NBY * 128;             // 192

  for (int L = 0; L < 3; ++L) {
    const float* wq  = Wq + (size_t)L * C * HD;
    const float* wk  = Wk + (size_t)L * C * HD;
    const float* wv  = Wv + (size_t)L * C * HD;
    const float* wo  = Wo + (size_t)L * HD * C;
    const float* bq_ = bq + (size_t)L * HD;
    const float* bk_ = bk + (size_t)L * HD;
    const float* bv_ = bv + (size_t)L * HD;
    const float* bo_ = bo + (size_t)L * C;
    const float* p   = P  + (size_t)L * M * C;
    const int leaky = (L < 2) ? 1 : 0;

    if (L == 0)
      k_kv<0><<<H * NB2, 256, 0, stream>>>(patch, nullptr, nparam, wk, bk_, wv, bv_, p, partial);
    else
      k_kv<1><<<H * NB2, 256, 0, stream>>>(nullptr, y, nparam, wk, bk_, wv, bv_, p, partial);

    k_redkv<<<H, 256, 0, stream>>>(partial, wo, ksumg, Gg);

    for (int r = 0; r < ROUNDS; ++r) {
      const int rbase = r * RNODES;
      if (L == 0)
        k_qp<0><<<1024, 256, 0, stream>>>(patch, nullptr, nparam, wq, bq_, p, ksumg, qpq, rbase);
      else
        k_qp<1><<<1024, 256, 0, stream>>>(nullptr, y, nparam, wq, bq_, p, ksumg, qpq, rbase);
      k_y<<<NBY, 1024, (15360 + 3840) * sizeof(double), stream>>>(
          qpq, Gg, bo_, leaky, y, psum, rbase, r);
    }

    k_norm_params<<<1, 128, 0, stream>>>(psum, ga + (size_t)L * C, be + (size_t)L * C,
                                         al + (size_t)L * C, nparam);
    if (L == 2)
      k_normalize<<<512, 256, 0, stream>>>(y, nparam, out);
  }
}